// Round 5
// baseline (16.138 us; speedup 1.0000x reference)
//
#include <hip/hip_runtime.h>
#include <hip/hip_bf16.h>

// Embedding lookup: out[row, :] = weight[idx[row], :]
//   idxes:  [8192] int32
//   weight: [50257, 1024] float32  (~206 MB)
//   out:    [8192, 1024] float32   (33.5 MB, write-once)
//
// Memory-bound gather. 512 blocks x 256 threads; each block copies 16 rows.
// Nontemporal loads AND stores: the gathered rows are read-once per dispatch
// (no intra-dispatch reuse -> L2 allocation is pure thrash), and the output
// is write-once. 16 independent 16B gathers in flight per thread.

#define FEATURES       1024
#define N_ROWS         (4 * 2048)
#define ROWS_PER_BLOCK 16
#define THREADS        (FEATURES / 4)   // 256: one 16B lane per column group

typedef float f32x4 __attribute__((ext_vector_type(4)));

__global__ void __launch_bounds__(THREADS)
Embedding_59124519797196_kernel(const int* __restrict__ idx,
                                const float* __restrict__ weight,
                                float* __restrict__ out) {
    const int t    = threadIdx.x;                    // 0..255
    const int base = blockIdx.x * ROWS_PER_BLOCK;    // first row of this block

    // Block-uniform index loads (scalarizable: one s_load_dwordx16-ish).
    int src[ROWS_PER_BLOCK];
#pragma unroll
    for (int i = 0; i < ROWS_PER_BLOCK; ++i)
        src[i] = idx[base + i];

    // Issue all gather loads before any store -> 16 loads in flight per thread.
    f32x4 v[ROWS_PER_BLOCK];
#pragma unroll
    for (int i = 0; i < ROWS_PER_BLOCK; ++i)
        v[i] = __builtin_nontemporal_load(
            reinterpret_cast<const f32x4*>(weight + (size_t)src[i] * FEATURES) + t);

    // Nontemporal stores: output is never re-read; don't allocate in L2.
#pragma unroll
    for (int i = 0; i < ROWS_PER_BLOCK; ++i)
        __builtin_nontemporal_store(
            v[i], reinterpret_cast<f32x4*>(out + (size_t)(base + i) * FEATURES) + t);
}

extern "C" void kernel_launch(void* const* d_in, const int* in_sizes, int n_in,
                              void* d_out, int out_size, void* d_ws, size_t ws_size,
                              hipStream_t stream) {
    const int*   idx    = (const int*)d_in[0];
    const float* weight = (const float*)d_in[1];
    float*       out    = (float*)d_out;

    dim3 grid(N_ROWS / ROWS_PER_BLOCK);  // 512
    dim3 block(THREADS);                 // 256

    Embedding_59124519797196_kernel<<<grid, block, 0, stream>>>(idx, weight, out);
}

// Round 6
// 14.471 us; speedup vs baseline: 1.1152x; 1.1152x over previous
//
#include <hip/hip_runtime.h>
#include <hip/hip_bf16.h>

// Embedding lookup: out[row, :] = weight[idx[row], :]
//   idxes:  [8192] int32
//   weight: [50257, 1024] float32  (~206 MB: L3-resident when warm)
//   out:    [8192, 1024] float32   (33.5 MB, write-once)
//
// Memory-bound gather. 1024 blocks x 256 threads; each block copies 8 rows.
// CACHED gather loads (weight stays warm in L3 across replays; nt loads
// measurably regress -13%) + NONTEMPORAL stores (output is write-once;
// bypassing L2 allocation measurably wins +10%).

#define FEATURES       1024
#define N_ROWS         (4 * 2048)
#define ROWS_PER_BLOCK 8
#define THREADS        (FEATURES / 4)   // 256: one 16B lane per column group

typedef float f32x4 __attribute__((ext_vector_type(4)));

__global__ void __launch_bounds__(THREADS)
Embedding_59124519797196_kernel(const int* __restrict__ idx,
                                const float* __restrict__ weight,
                                float* __restrict__ out) {
    const int t    = threadIdx.x;                    // 0..255
    const int base = blockIdx.x * ROWS_PER_BLOCK;    // first row of this block

    // Block-uniform index loads (scalarized to s_load by the compiler).
    int src[ROWS_PER_BLOCK];
#pragma unroll
    for (int i = 0; i < ROWS_PER_BLOCK; ++i)
        src[i] = idx[base + i];

    // Issue all gather loads before any store -> 8 loads in flight per thread.
    f32x4 v[ROWS_PER_BLOCK];
#pragma unroll
    for (int i = 0; i < ROWS_PER_BLOCK; ++i)
        v[i] = reinterpret_cast<const f32x4*>(weight + (size_t)src[i] * FEATURES)[t];

    // Nontemporal stores: output is never re-read; don't allocate in L2.
#pragma unroll
    for (int i = 0; i < ROWS_PER_BLOCK; ++i)
        __builtin_nontemporal_store(
            v[i], reinterpret_cast<f32x4*>(out + (size_t)(base + i) * FEATURES) + t);
}

extern "C" void kernel_launch(void* const* d_in, const int* in_sizes, int n_in,
                              void* d_out, int out_size, void* d_ws, size_t ws_size,
                              hipStream_t stream) {
    const int*   idx    = (const int*)d_in[0];
    const float* weight = (const float*)d_in[1];
    float*       out    = (float*)d_out;

    dim3 grid(N_ROWS / ROWS_PER_BLOCK);  // 1024
    dim3 block(THREADS);                 // 256

    Embedding_59124519797196_kernel<<<grid, block, 0, stream>>>(idx, weight, out);
}